// Round 5
// baseline (203.808 us; speedup 1.0000x reference)
//
#include <hip/hip_runtime.h>

// NavierStokesLoss: fused jet-propagation (8 channels/point) through
// 4->256->256->5 tanh MLP, bf16 MFMA for the 256x256 layer, f32 elsewhere.
// R5: two-subtile software pipeline inside each block (BP=16 = 2 x 8 points).
// Each barrier interval mixes MFMA work of one subtile with VALU work of the
// other, so the MFMA / VALU / LDS pipes overlap instead of serializing.

#define NPTS 65536
#define BP   16
#define NBLK (NPTS / BP)      // 4096
#define KPAD 264              // padded k-stride of W2^T (bf16 elems)
#define W3T_OFF 135168        // 256*264*2
#define PART_OFF 143360
#define TSZ 32768             // bytes per 64-row subtile

typedef short s16x8 __attribute__((ext_vector_type(8)));
typedef float f32x4 __attribute__((ext_vector_type(4)));

static __device__ __forceinline__ unsigned short f2bf(float f){
  unsigned int u = __float_as_uint(f);
  u = (u + 0x7FFFu + ((u >> 16) & 1u)) >> 16;   // RNE
  return (unsigned short)u;
}
static __device__ __forceinline__ unsigned cvtpk_bf16(float lo, float hi){
  unsigned r;
  asm("v_cvt_pk_bf16_f32 %0, %1, %2" : "=v"(r) : "v"(lo), "v"(hi));
  return r;
}
static __device__ __forceinline__ float fast_tanh(float x){
  float e = __builtin_amdgcn_exp2f(x * 2.8853900817779268f);   // exp(2x)
  return 1.f - 2.f * __builtin_amdgcn_rcpf(e + 1.f);
}

// W2 (256x256 f32, [k][j]) -> w2t bf16 [j][KPAD] (transposed, padded)
__global__ void prep_w2t(const float* __restrict__ W2, unsigned short* __restrict__ w2t){
  int k = blockIdx.x, j = threadIdx.x;
  w2t[j * KPAD + k] = f2bf(W2[k * 256 + j]);
}

// W3 (256x5 f32, [k][n]) -> w3t bf16 [16][256] (transposed, rows 5..15 zero)
__global__ void prep_w3t(const float* __restrict__ W3, unsigned short* __restrict__ w3t){
  int idx = blockIdx.x * 256 + threadIdx.x;
  int n = idx >> 8, k = idx & 255;
  w3t[n * 256 + k] = (n < 5) ? f2bf(W3[k * 5 + n]) : (unsigned short)0;
}

// per-point residual assembly from one subtile's GEMM3 writebacks
static __device__ __forceinline__ float2 tail_point(const unsigned char* base, int p,
                                                    const float* __restrict__ b3, float vis){
  float o[8][5];
  #pragma unroll
  for (int c = 0; c < 8; ++c){
    int row = ((p & 4) << 3) + ((c & 4) << 2) + ((p & 3) << 2) + (c & 3);
    int swz = (row & 7) << 4;
    f32x4 v4 = *(const f32x4*)(base + row*512 + swz);
    o[c][0] = v4[0]; o[c][1] = v4[1]; o[c][2] = v4[2]; o[c][3] = v4[3];
    o[c][4] = *(const float*)(base + row*512 + (16 ^ swz));
  }
  #pragma unroll
  for (int m = 0; m < 5; ++m) o[0][m] += b3[m];
  float u0 = o[0][0], u1 = o[0][1], u2 = o[0][2];
  float rho = 1000.f * (1.f + 0.1f * fast_tanh(o[0][4]));
  float rr  = __builtin_amdgcn_rcpf(rho);
  float conv0 = u0*o[1][0] + u1*o[2][0] + u2*o[3][0];
  float conv1 = u0*o[1][1] + u1*o[2][1] + u2*o[3][1];
  float conv2 = u0*o[1][2] + u1*o[2][2] + u2*o[3][2];
  float lap0 = o[5][0] + o[6][0] + o[7][0];
  float lap1 = o[5][1] + o[6][1] + o[7][1];
  float lap2 = o[5][2] + o[6][2] + o[7][2];
  float R0 = o[4][0] + conv0 + o[1][3]*rr - vis*lap0;
  float R1 = o[4][1] + conv1 + o[2][3]*rr - vis*lap1 + 9.81f;
  float R2 = o[4][2] + conv2 + o[3][3]*rr - vis*lap2;
  float Rc = o[1][0] + o[2][1] + o[3][2];
  float2 res;
  res.x = R0*R0 + R1*R1 + R2*R2;
  res.y = Rc*Rc;
  return res;
}

// Row layout of a 64x256 jet subtile:
//   row(p,c) = (p&4)*8 + (c&4)*4 + (p&3)*4 + (c&3)
__launch_bounds__(512, 4)
__global__ void ns_main(const float* __restrict__ pts, const float* __restrict__ times,
                        const float* __restrict__ visc,
                        const float* __restrict__ W1, const float* __restrict__ b1,
                        const float* __restrict__ b2, const float* __restrict__ b3,
                        const unsigned short* __restrict__ w2t,
                        const unsigned short* __restrict__ w3t,
                        float* __restrict__ parts){
  __shared__ __align__(16) unsigned char sA[2 * TSZ];   // 64 KiB

  const int t   = threadIdx.x;
  const int blk = blockIdx.x;
  const int wid = t >> 6, lane = t & 63;
  const int g = lane >> 4, r16 = lane & 15;
  const int wr = wid >> 2, wc = wid & 3;     // 2x4 wave grid over 64x256
  const int xorv = (r16 & 7) << 4;

  // ---- shared-by-both-subtiles register state ----
  const int p8 = t >> 6;            // point within subtile (layer-1 mapping)
  const int jo = (t & 63) << 2;     // 4 consecutive j per thread
  float4 wa  = *(const float4*)(W1 + jo);
  float4 wb  = *(const float4*)(W1 + 256 + jo);
  float4 wc4 = *(const float4*)(W1 + 512 + jo);
  float4 wd  = *(const float4*)(W1 + 768 + jo);
  float4 bb  = *(const float4*)(b1 + jo);
  int n0 = blk*BP + p8, n1 = n0 + 8;
  float4 z0v = make_float4(pts[n0*3], pts[n0*3+1], pts[n0*3+2], times[n0]);
  float4 z1v = make_float4(pts[n1*3], pts[n1*3+1], pts[n1*3+2], times[n1]);

  const unsigned char* w2tB = (const unsigned char*)w2t;
  const unsigned char* bp0 = w2tB + (((wc*64 +  0 + r16)*KPAD + g*8) << 1);
  const unsigned char* bp1 = w2tB + (((wc*64 + 16 + r16)*KPAD + g*8) << 1);
  const unsigned char* bp2 = w2tB + (((wc*64 + 32 + r16)*KPAD + g*8) << 1);
  const unsigned char* bp3 = w2tB + (((wc*64 + 48 + r16)*KPAD + g*8) << 1);
  float b2c[4];
  #pragma unroll
  for (int nt = 0; nt < 4; ++nt) b2c[nt] = b2[wc*64 + nt*16 + r16];
  const unsigned char* w3tB = (const unsigned char*)w3t + ((r16*256 + g*8) << 1);

  f32x4 acc0[2][4], acc1[2][4];

#define L1_TILE(ZV, BASE) do {                                                  \
    float th_[4], sg_[4], m2_[4];                                               \
    _Pragma("unroll")                                                           \
    for (int jj = 0; jj < 4; ++jj){                                             \
      float a_ = (&bb.x)[jj] + (ZV).x*(&wa.x)[jj] + (ZV).y*(&wb.x)[jj]          \
                             + (ZV).z*(&wc4.x)[jj] + (ZV).w*(&wd.x)[jj];        \
      float h_ = fast_tanh(a_);                                                 \
      th_[jj] = h_; sg_[jj] = 1.f - h_*h_; m2_[jj] = -2.f*h_*sg_[jj];           \
    }                                                                           \
    _Pragma("unroll")                                                           \
    for (int c = 0; c < 8; ++c){                                                \
      float x_[4];                                                              \
      _Pragma("unroll")                                                         \
      for (int jj = 0; jj < 4; ++jj){                                           \
        float w0_ = (&wa.x)[jj], w1_ = (&wb.x)[jj], w2_ = (&wc4.x)[jj];         \
        float v_;                                                               \
        if      (c == 0) v_ = th_[jj];                                          \
        else if (c == 1) v_ = sg_[jj]*w0_;                                      \
        else if (c == 2) v_ = sg_[jj]*w1_;                                      \
        else if (c == 3) v_ = sg_[jj]*w2_;                                      \
        else if (c == 4) v_ = sg_[jj]*(&wd.x)[jj];                              \
        else if (c == 5) v_ = m2_[jj]*w0_*w0_;                                  \
        else if (c == 6) v_ = m2_[jj]*w1_*w1_;                                  \
        else             v_ = m2_[jj]*w2_*w2_;                                  \
        x_[jj] = v_;                                                            \
      }                                                                         \
      int row_ = ((p8 & 4) << 3) + ((c & 4) << 2) + ((p8 & 3) << 2) + (c & 3);  \
      int off_ = row_*512 + ((jo << 1) ^ ((row_ & 7) << 4));                    \
      uint2 v2_; v2_.x = cvtpk_bf16(x_[0], x_[1]); v2_.y = cvtpk_bf16(x_[2], x_[3]); \
      *(uint2*)((BASE) + off_) = v2_;                                           \
    }                                                                           \
  } while (0)

#define GEMM2_TILE(BASE, ACC) do {                                              \
    int abase_ = (wr*32 + r16)*512;                                             \
    _Pragma("unroll")                                                           \
    for (int ks = 0; ks < 8; ++ks){                                             \
      int k0_ = ks*32;                                                          \
      int X_  = ((k0_ << 1) + (g << 4)) ^ xorv;                                 \
      s16x8 a0_ = *(const s16x8*)((BASE) + abase_ + X_);                        \
      s16x8 a1_ = *(const s16x8*)((BASE) + abase_ + 8192 + X_);                 \
      s16x8 q0_ = *(const s16x8*)(bp0 + (k0_ << 1));                            \
      s16x8 q1_ = *(const s16x8*)(bp1 + (k0_ << 1));                            \
      s16x8 q2_ = *(const s16x8*)(bp2 + (k0_ << 1));                            \
      s16x8 q3_ = *(const s16x8*)(bp3 + (k0_ << 1));                            \
      __builtin_amdgcn_s_setprio(1);                                            \
      ACC[0][0] = __builtin_amdgcn_mfma_f32_16x16x32_bf16(a0_, q0_, ACC[0][0], 0, 0, 0); \
      ACC[1][0] = __builtin_amdgcn_mfma_f32_16x16x32_bf16(a1_, q0_, ACC[1][0], 0, 0, 0); \
      ACC[0][1] = __builtin_amdgcn_mfma_f32_16x16x32_bf16(a0_, q1_, ACC[0][1], 0, 0, 0); \
      ACC[1][1] = __builtin_amdgcn_mfma_f32_16x16x32_bf16(a1_, q1_, ACC[1][1], 0, 0, 0); \
      ACC[0][2] = __builtin_amdgcn_mfma_f32_16x16x32_bf16(a0_, q2_, ACC[0][2], 0, 0, 0); \
      ACC[1][2] = __builtin_amdgcn_mfma_f32_16x16x32_bf16(a1_, q2_, ACC[1][2], 0, 0, 0); \
      ACC[0][3] = __builtin_amdgcn_mfma_f32_16x16x32_bf16(a0_, q3_, ACC[0][3], 0, 0, 0); \
      ACC[1][3] = __builtin_amdgcn_mfma_f32_16x16x32_bf16(a1_, q3_, ACC[1][3], 0, 0, 0); \
      __builtin_amdgcn_s_setprio(0);                                            \
    }                                                                           \
  } while (0)

#define RC_TILE(BASE, ACC) do {                                                 \
    _Pragma("unroll")                                                           \
    for (int nt = 0; nt < 4; ++nt){                                             \
      f32x4 v_ = ACC[0][nt];      /* channels 0..3: value, dx, dy, dz */        \
      f32x4 w_ = ACC[1][nt];      /* channels 4..7: dt, dxx, dyy, dzz */        \
      float gv_ = fast_tanh(v_[0] + b2c[nt]);                                   \
      float s2_ = 1.f - gv_*gv_;                                                \
      float t2_ = -2.f * gv_ * s2_;                                             \
      float r0_ = gv_,       r1_ = s2_*v_[1], r2_ = s2_*v_[2], r3_ = s2_*v_[3]; \
      float r4_ = s2_*w_[0];                                                    \
      float r5_ = fmaf(t2_*v_[1], v_[1], s2_*w_[1]);                            \
      float r6_ = fmaf(t2_*v_[2], v_[2], s2_*w_[2]);                            \
      float r7_ = fmaf(t2_*v_[3], v_[3], s2_*w_[3]);                            \
      int colb_ = (wc*64 + nt*16 + r16) << 1;                                   \
      int rb_   = (wr*32 + g*4)*512;                                            \
      unsigned u_;                                                              \
      u_ = cvtpk_bf16(r0_, r4_);                                                \
      *(unsigned short*)((BASE) + rb_        + (colb_ ^ ((((g&1)<<2)+0) << 4)))        = (unsigned short)u_; \
      *(unsigned short*)((BASE) + rb_        + (colb_ ^ ((((g&1)<<2)+0) << 4)) + 8192) = (unsigned short)(u_ >> 16); \
      u_ = cvtpk_bf16(r1_, r5_);                                                \
      *(unsigned short*)((BASE) + rb_ + 512  + (colb_ ^ ((((g&1)<<2)+1) << 4)))        = (unsigned short)u_; \
      *(unsigned short*)((BASE) + rb_ + 512  + (colb_ ^ ((((g&1)<<2)+1) << 4)) + 8192) = (unsigned short)(u_ >> 16); \
      u_ = cvtpk_bf16(r2_, r6_);                                                \
      *(unsigned short*)((BASE) + rb_ + 1024 + (colb_ ^ ((((g&1)<<2)+2) << 4)))        = (unsigned short)u_; \
      *(unsigned short*)((BASE) + rb_ + 1024 + (colb_ ^ ((((g&1)<<2)+2) << 4)) + 8192) = (unsigned short)(u_ >> 16); \
      u_ = cvtpk_bf16(r3_, r7_);                                                \
      *(unsigned short*)((BASE) + rb_ + 1536 + (colb_ ^ ((((g&1)<<2)+3) << 4)))        = (unsigned short)u_; \
      *(unsigned short*)((BASE) + rb_ + 1536 + (colb_ ^ ((((g&1)<<2)+3) << 4)) + 8192) = (unsigned short)(u_ >> 16); \
    }                                                                           \
  } while (0)

#define GEMM3_TILE(BASE) do {                                                   \
    f32x4 a3c_ = (f32x4){0.f, 0.f, 0.f, 0.f};                                   \
    int rbase_ = (wid*16 + r16)*512;                                            \
    _Pragma("unroll")                                                           \
    for (int ks = 0; ks < 8; ++ks){                                             \
      int k0_ = ks*32;                                                          \
      int X_  = ((k0_ << 1) + (g << 4)) ^ xorv;                                 \
      s16x8 av_ = *(const s16x8*)((BASE) + rbase_ + X_);                        \
      s16x8 bv_ = *(const s16x8*)(w3tB + (k0_ << 1));                           \
      a3c_ = __builtin_amdgcn_mfma_f32_16x16x32_bf16(av_, bv_, a3c_, 0, 0, 0);  \
    }                                                                           \
    if (r16 < 5){                                                               \
      _Pragma("unroll")                                                         \
      for (int q = 0; q < 4; ++q){                                              \
        int row_ = wid*16 + g*4 + q;                                            \
        *(float*)((BASE) + row_*512 + ((r16 << 2) ^ ((row_ & 7) << 4))) = a3c_[q]; \
      }                                                                         \
    }                                                                           \
  } while (0)

  // ---------------- P0: layer-1 of T0 ----------------
  L1_TILE(z0v, sA);
  __syncthreads();

  // ---------------- P1: GEMM2(T0) || layer-1(T1) ----------------
  #pragma unroll
  for (int a = 0; a < 2; ++a)
    #pragma unroll
    for (int b = 0; b < 4; ++b)
      acc0[a][b] = (f32x4){0.f, 0.f, 0.f, 0.f};
  GEMM2_TILE(sA, acc0);
  L1_TILE(z1v, sA + TSZ);
  __syncthreads();

  // ---------------- P2: recombine(T0) || GEMM2(T1) ----------------
  #pragma unroll
  for (int a = 0; a < 2; ++a)
    #pragma unroll
    for (int b = 0; b < 4; ++b)
      acc1[a][b] = (f32x4){0.f, 0.f, 0.f, 0.f};
  RC_TILE(sA, acc0);
  GEMM2_TILE(sA + TSZ, acc1);
  __syncthreads();

  // ---------------- P3: recombine(T1) || GEMM3(T0) ----------------
  RC_TILE(sA + TSZ, acc1);
  if (wid < 4) GEMM3_TILE(sA);
  __syncthreads();

  // ---------------- P4: GEMM3(T1) || tail(T0) ----------------
  float2 s0 = make_float2(0.f, 0.f);
  if (wid < 4) GEMM3_TILE(sA + TSZ);
  if (wid == 7 && lane < 8)
    s0 = tail_point(sA, lane, b3, visc[blk*BP + lane]);
  __syncthreads();

  // ---------------- P5: tail(T1) + block reduce ----------------
  if (wid == 7){
    float2 s1 = make_float2(0.f, 0.f);
    if (lane < 8)
      s1 = tail_point(sA + TSZ, lane, b3, visc[blk*BP + 8 + lane]);
    float m = s0.x + s1.x, c = s0.y + s1.y;
    #pragma unroll
    for (int off = 1; off < 8; off <<= 1){
      m += __shfl_xor(m, off, 64);
      c += __shfl_xor(c, off, 64);
    }
    if (lane == 0){
      float2 pr; pr.x = m; pr.y = c;
      *(float2*)(parts + blk*2) = pr;
    }
  }
#undef L1_TILE
#undef GEMM2_TILE
#undef RC_TILE
#undef GEMM3_TILE
}

__global__ void ns_reduce(const float* __restrict__ parts, float* __restrict__ out){
  int t = threadIdx.x;
  float a = 0.f, b = 0.f;
  for (int i = t; i < NBLK; i += 256){ a += parts[2*i]; b += parts[2*i + 1]; }
  #pragma unroll
  for (int off = 32; off; off >>= 1){
    a += __shfl_down(a, off, 64);
    b += __shfl_down(b, off, 64);
  }
  __shared__ float sa[4], sb[4];
  int wid = t >> 6, lane = t & 63;
  if (lane == 0){ sa[wid] = a; sb[wid] = b; }
  __syncthreads();
  if (t == 0){
    float A = sa[0] + sa[1] + sa[2] + sa[3];
    float B = sb[0] + sb[1] + sb[2] + sb[3];
    float mom  = A / (float)NPTS;
    float cont = B / (float)NPTS;
    out[0] = mom + 10.f * cont;
    out[1] = mom;
    out[2] = cont;
  }
}

extern "C" void kernel_launch(void* const* d_in, const int* in_sizes, int n_in,
                              void* d_out, int out_size, void* d_ws, size_t ws_size,
                              hipStream_t stream) {
  const float* pts   = (const float*)d_in[0];
  const float* times = (const float*)d_in[1];
  const float* visc  = (const float*)d_in[2];
  const float* W1    = (const float*)d_in[3];
  const float* b1    = (const float*)d_in[4];
  const float* W2    = (const float*)d_in[5];
  const float* b2    = (const float*)d_in[6];
  const float* W3    = (const float*)d_in[7];
  const float* b3    = (const float*)d_in[8];
  float* out = (float*)d_out;

  unsigned short* w2t = (unsigned short*)d_ws;
  unsigned short* w3t = (unsigned short*)((char*)d_ws + W3T_OFF);
  float* parts        = (float*)((char*)d_ws + PART_OFF);

  prep_w2t<<<256, 256, 0, stream>>>(W2, w2t);
  prep_w3t<<<16, 256, 0, stream>>>(W3, w3t);
  ns_main<<<NBLK, 512, 0, stream>>>(pts, times, visc, W1, b1, b2, b3, w2t, w3t, parts);
  ns_reduce<<<1, 256, 0, stream>>>(parts, out);
}

// Round 6
// 129.788 us; speedup vs baseline: 1.5703x; 1.5703x over previous
//
#include <hip/hip_runtime.h>

// NavierStokesLoss: fused jet-propagation (8 channels/point) through
// 4->256->256->5 tanh MLP, bf16 MFMA, f32 elsewhere.
// R6: persistent pipelined kernel. 256 blocks (1/CU), each runs 32 tiles of
// 8 points through a 3-buffer LDS ring with 2 barriers/tile:
//   int1: GEMM2(t)            || layer1(t+1)
//   int2: recombine(t)        || GEMM3(t-1) + in-register tail
// GEMM3+tail keep everything in registers (shfl assembly, per-lane loss
// accumulators across tiles) -> no writeback phase, no 4th buffer.

#define NPTS 65536
#define TPB  8                 // points per tile
#define NBLOCKS 256
#define TILES 32               // tiles per block: 256*32*8 = 65536
#define KPAD 264
#define W3T_OFF 135168         // 256*264*2
#define PART_OFF 143360
#define TSZ 32768              // bytes per 64-row jet tile

typedef short s16x8 __attribute__((ext_vector_type(8)));
typedef float f32x4 __attribute__((ext_vector_type(4)));

static __device__ __forceinline__ unsigned short f2bf(float f){
  unsigned int u = __float_as_uint(f);
  u = (u + 0x7FFFu + ((u >> 16) & 1u)) >> 16;   // RNE
  return (unsigned short)u;
}
static __device__ __forceinline__ unsigned cvtpk_bf16(float lo, float hi){
  unsigned r;
  asm("v_cvt_pk_bf16_f32 %0, %1, %2" : "=v"(r) : "v"(lo), "v"(hi));
  return r;
}
static __device__ __forceinline__ float fast_tanh(float x){
  float e = __builtin_amdgcn_exp2f(x * 2.8853900817779268f);   // exp(2x)
  return 1.f - 2.f * __builtin_amdgcn_rcpf(e + 1.f);
}

__global__ void prep_w2t(const float* __restrict__ W2, unsigned short* __restrict__ w2t){
  int k = blockIdx.x, j = threadIdx.x;
  w2t[j * KPAD + k] = f2bf(W2[k * 256 + j]);
}
__global__ void prep_w3t(const float* __restrict__ W3, unsigned short* __restrict__ w3t){
  int idx = blockIdx.x * 256 + threadIdx.x;
  int n = idx >> 8, k = idx & 255;
  w3t[n * 256 + k] = (n < 5) ? f2bf(W3[k * 5 + n]) : (unsigned short)0;
}

// Jet-tile row layout (64 rows x 256 bf16, 512B XOR-swizzled rows):
//   row(p,c) = (p&4)*8 + (c&4)*4 + (p&3)*4 + (c&3)      (proven in R4)
__launch_bounds__(512, 2)
__global__ void ns_main(const float* __restrict__ pts, const float* __restrict__ times,
                        const float* __restrict__ visc,
                        const float* __restrict__ W1, const float* __restrict__ b1,
                        const float* __restrict__ b2, const float* __restrict__ b3,
                        const unsigned short* __restrict__ w2t,
                        const unsigned short* __restrict__ w3t,
                        float* __restrict__ parts){
  __shared__ __align__(16) unsigned char sA[3 * TSZ];   // 96 KiB ring

  const int t   = threadIdx.x;
  const int blk = blockIdx.x;
  const int wid = t >> 6, lane = t & 63;
  const int g = lane >> 4, r16 = lane & 15;
  const int wr = wid >> 2, wc = wid & 3;     // 2x4 wave grid over 64x256
  const int xorv = (r16 & 7) << 4;

  // ---------------- persistent state ----------------
  const int p8 = t >> 6;            // point within tile (layer-1 mapping)
  const int jo = (t & 63) << 2;     // 4 consecutive j per thread
  const float4 wa  = *(const float4*)(W1 + jo);
  const float4 wb  = *(const float4*)(W1 + 256 + jo);
  const float4 wc4 = *(const float4*)(W1 + 512 + jo);
  const float4 wd  = *(const float4*)(W1 + 768 + jo);
  const float4 bb  = *(const float4*)(b1 + jo);

  const unsigned char* w2tB = (const unsigned char*)w2t;
  const unsigned char* bp0 = w2tB + (((wc*64 +  0 + r16)*KPAD + g*8) << 1);
  const unsigned char* bp1 = w2tB + (((wc*64 + 16 + r16)*KPAD + g*8) << 1);
  const unsigned char* bp2 = w2tB + (((wc*64 + 32 + r16)*KPAD + g*8) << 1);
  const unsigned char* bp3 = w2tB + (((wc*64 + 48 + r16)*KPAD + g*8) << 1);
  float b2c[4];
  #pragma unroll
  for (int nt = 0; nt < 4; ++nt) b2c[nt] = b2[wc*64 + nt*16 + r16];
  const unsigned char* w3tB = (const unsigned char*)w3t + ((r16*256 + g*8) << 1);
  const float b3v = (r16 < 5) ? b3[r16] : 0.f;

  // GEMM3 per-lane row addressing: wave wid (role: waves 4-7) owns points
  // 2*(wid&3), 2*(wid&3)+1; lane r16 -> (pt parity, channel half, c3).
  const int w3i = wid & 3;
  const int ptL = 2*w3i + ((r16 >> 2) & 1);
  const int jrow = ((ptL & 4) << 3) + ((ptL & 3) << 2) + (r16 & 3) + ((r16 >> 3) << 4);
  const int g3off = jrow * 512;
  const int g3sw  = (jrow & 7) << 4;

  float accM = 0.f, accC = 0.f;

  unsigned char *jA = sA, *jB = sA + TSZ, *jC = sA + 2*TSZ;

#define L1_TILE(NBASE, BASE) do {                                               \
    int n_ = (NBASE) + p8;                                                      \
    float z0_ = pts[n_*3+0], z1_ = pts[n_*3+1], z2_ = pts[n_*3+2], z3_ = times[n_]; \
    float th_[4], sg_[4], m2_[4];                                               \
    _Pragma("unroll")                                                           \
    for (int jj = 0; jj < 4; ++jj){                                             \
      float a_ = (&bb.x)[jj] + z0_*(&wa.x)[jj] + z1_*(&wb.x)[jj]                \
                             + z2_*(&wc4.x)[jj] + z3_*(&wd.x)[jj];              \
      float h_ = fast_tanh(a_);                                                 \
      th_[jj] = h_; sg_[jj] = 1.f - h_*h_; m2_[jj] = -2.f*h_*sg_[jj];           \
    }                                                                           \
    _Pragma("unroll")                                                           \
    for (int c = 0; c < 8; ++c){                                                \
      float x_[4];                                                              \
      _Pragma("unroll")                                                         \
      for (int jj = 0; jj < 4; ++jj){                                           \
        float w0_ = (&wa.x)[jj], w1_ = (&wb.x)[jj], w2_ = (&wc4.x)[jj];         \
        float v_;                                                               \
        if      (c == 0) v_ = th_[jj];                                          \
        else if (c == 1) v_ = sg_[jj]*w0_;                                      \
        else if (c == 2) v_ = sg_[jj]*w1_;                                      \
        else if (c == 3) v_ = sg_[jj]*w2_;                                      \
        else if (c == 4) v_ = sg_[jj]*(&wd.x)[jj];                              \
        else if (c == 5) v_ = m2_[jj]*w0_*w0_;                                  \
        else if (c == 6) v_ = m2_[jj]*w1_*w1_;                                  \
        else             v_ = m2_[jj]*w2_*w2_;                                  \
        x_[jj] = v_;                                                            \
      }                                                                         \
      int row_ = ((p8 & 4) << 3) + ((c & 4) << 2) + ((p8 & 3) << 2) + (c & 3);  \
      int off_ = row_*512 + (((jo << 1)) ^ ((row_ & 7) << 4));                  \
      uint2 v2_; v2_.x = cvtpk_bf16(x_[0], x_[1]); v2_.y = cvtpk_bf16(x_[2], x_[3]); \
      *(uint2*)((BASE) + off_) = v2_;                                           \
    }                                                                           \
  } while (0)

#define GEMM2_TILE(BASE, ACC) do {                                              \
    int abase_ = (wr*32 + r16)*512;                                             \
    s16x8 bc0_ = *(const s16x8*)(bp0), bc1_ = *(const s16x8*)(bp1);             \
    s16x8 bc2_ = *(const s16x8*)(bp2), bc3_ = *(const s16x8*)(bp3);             \
    _Pragma("unroll")                                                           \
    for (int ks = 0; ks < 8; ++ks){                                             \
      int X_ = ((ks*64) + (g << 4)) ^ xorv;                                     \
      s16x8 a0_ = *(const s16x8*)((BASE) + abase_ + X_);                        \
      s16x8 a1_ = *(const s16x8*)((BASE) + abase_ + 8192 + X_);                 \
      s16x8 bn0_, bn1_, bn2_, bn3_;                                             \
      if (ks < 7){                                                              \
        bn0_ = *(const s16x8*)(bp0 + (ks+1)*64);                                \
        bn1_ = *(const s16x8*)(bp1 + (ks+1)*64);                                \
        bn2_ = *(const s16x8*)(bp2 + (ks+1)*64);                                \
        bn3_ = *(const s16x8*)(bp3 + (ks+1)*64);                                \
      }                                                                         \
      __builtin_amdgcn_s_setprio(1);                                            \
      ACC[0][0] = __builtin_amdgcn_mfma_f32_16x16x32_bf16(a0_, bc0_, ACC[0][0], 0, 0, 0); \
      ACC[1][0] = __builtin_amdgcn_mfma_f32_16x16x32_bf16(a1_, bc0_, ACC[1][0], 0, 0, 0); \
      ACC[0][1] = __builtin_amdgcn_mfma_f32_16x16x32_bf16(a0_, bc1_, ACC[0][1], 0, 0, 0); \
      ACC[1][1] = __builtin_amdgcn_mfma_f32_16x16x32_bf16(a1_, bc1_, ACC[1][1], 0, 0, 0); \
      ACC[0][2] = __builtin_amdgcn_mfma_f32_16x16x32_bf16(a0_, bc2_, ACC[0][2], 0, 0, 0); \
      ACC[1][2] = __builtin_amdgcn_mfma_f32_16x16x32_bf16(a1_, bc2_, ACC[1][2], 0, 0, 0); \
      ACC[0][3] = __builtin_amdgcn_mfma_f32_16x16x32_bf16(a0_, bc3_, ACC[0][3], 0, 0, 0); \
      ACC[1][3] = __builtin_amdgcn_mfma_f32_16x16x32_bf16(a1_, bc3_, ACC[1][3], 0, 0, 0); \
      __builtin_amdgcn_s_setprio(0);                                            \
      bc0_ = bn0_; bc1_ = bn1_; bc2_ = bn2_; bc3_ = bn3_;                       \
    }                                                                           \
  } while (0)

#define RC_TILE(BASE, ACC) do {                                                 \
    _Pragma("unroll")                                                           \
    for (int nt = 0; nt < 4; ++nt){                                             \
      f32x4 v_ = ACC[0][nt];      /* channels 0..3: value, dx, dy, dz */        \
      f32x4 w_ = ACC[1][nt];      /* channels 4..7: dt, dxx, dyy, dzz */        \
      float gv_ = fast_tanh(v_[0] + b2c[nt]);                                   \
      float s2_ = 1.f - gv_*gv_;                                                \
      float t2_ = -2.f * gv_ * s2_;                                             \
      float r0_ = gv_,       r1_ = s2_*v_[1], r2_ = s2_*v_[2], r3_ = s2_*v_[3]; \
      float r4_ = s2_*w_[0];                                                    \
      float r5_ = fmaf(t2_*v_[1], v_[1], s2_*w_[1]);                            \
      float r6_ = fmaf(t2_*v_[2], v_[2], s2_*w_[2]);                            \
      float r7_ = fmaf(t2_*v_[3], v_[3], s2_*w_[3]);                            \
      int colb_ = (wc*64 + nt*16 + r16) << 1;                                   \
      int rb_   = (wr*32 + g*4)*512;                                            \
      unsigned u_;                                                              \
      u_ = cvtpk_bf16(r0_, r4_);                                                \
      *(unsigned short*)((BASE) + rb_        + (colb_ ^ ((((g&1)<<2)+0) << 4)))        = (unsigned short)u_; \
      *(unsigned short*)((BASE) + rb_        + (colb_ ^ ((((g&1)<<2)+0) << 4)) + 8192) = (unsigned short)(u_ >> 16); \
      u_ = cvtpk_bf16(r1_, r5_);                                                \
      *(unsigned short*)((BASE) + rb_ + 512  + (colb_ ^ ((((g&1)<<2)+1) << 4)))        = (unsigned short)u_; \
      *(unsigned short*)((BASE) + rb_ + 512  + (colb_ ^ ((((g&1)<<2)+1) << 4)) + 8192) = (unsigned short)(u_ >> 16); \
      u_ = cvtpk_bf16(r2_, r6_);                                                \
      *(unsigned short*)((BASE) + rb_ + 1024 + (colb_ ^ ((((g&1)<<2)+2) << 4)))        = (unsigned short)u_; \
      *(unsigned short*)((BASE) + rb_ + 1024 + (colb_ ^ ((((g&1)<<2)+2) << 4)) + 8192) = (unsigned short)(u_ >> 16); \
      u_ = cvtpk_bf16(r3_, r7_);                                                \
      *(unsigned short*)((BASE) + rb_ + 1536 + (colb_ ^ ((((g&1)<<2)+3) << 4)))        = (unsigned short)u_; \
      *(unsigned short*)((BASE) + rb_ + 1536 + (colb_ ^ ((((g&1)<<2)+3) << 4)) + 8192) = (unsigned short)(u_ >> 16); \
    }                                                                           \
  } while (0)

  // GEMM3 + fully in-register residual assembly (waves 4-7)
#define GEMM3_TAIL(BASE, NBASE) do {                                            \
    f32x4 a3_ = (f32x4){0.f, 0.f, 0.f, 0.f};                                    \
    _Pragma("unroll")                                                           \
    for (int ks = 0; ks < 8; ++ks){                                             \
      int X_ = ((ks*64) + (g << 4)) ^ g3sw;                                     \
      s16x8 av_ = *(const s16x8*)((BASE) + g3off + X_);                         \
      s16x8 bv_ = *(const s16x8*)(w3tB + ks*64);                                \
      a3_ = __builtin_amdgcn_mfma_f32_16x16x32_bf16(av_, bv_, a3_, 0, 0, 0);    \
    }                                                                           \
    float o4_ = __shfl_xor(a3_[0], 32, 64);                                     \
    float o5_ = __shfl_xor(a3_[1], 32, 64);                                     \
    float o6_ = __shfl_xor(a3_[2], 32, 64);                                     \
    float o7_ = __shfl_xor(a3_[3], 32, 64);                                     \
    float o0_ = a3_[0] + b3v, o1_ = a3_[1], o2_ = a3_[2], o3_ = a3_[3];         \
    int sl_ = lane & 16;                                                        \
    float u0_ = __shfl(o0_, sl_ | 0, 64);                                       \
    float u1_ = __shfl(o0_, sl_ | 1, 64);                                       \
    float u2_ = __shfl(o0_, sl_ | 2, 64);                                       \
    float rhoA_ = __shfl(o0_, sl_ | 4, 64);                                     \
    float gpx_ = __shfl(o1_, sl_ | 3, 64);                                      \
    float gpy_ = __shfl(o2_, sl_ | 3, 64);                                      \
    float gpz_ = __shfl(o3_, sl_ | 3, 64);                                      \
    float c00_ = __shfl(o1_, sl_ | 0, 64);                                      \
    float c11_ = __shfl(o2_, sl_ | 1, 64);                                      \
    float c22_ = __shfl(o3_, sl_ | 2, 64);                                      \
    float rho_ = 1000.f * (1.f + 0.1f * fast_tanh(rhoA_));                      \
    float rr_  = __builtin_amdgcn_rcpf(rho_);                                   \
    float vis_ = visc[(NBASE) + ptL];                                           \
    float lap_ = o5_ + o6_ + o7_;                                               \
    float cv_  = u0_*o1_ + u1_*o2_ + u2_*o3_;                                   \
    float gp_  = (r16 == 0) ? gpx_ : ((r16 == 1) ? gpy_ : gpz_);                \
    float R_   = o4_ + cv_ + gp_*rr_ - vis_*lap_ + ((r16 == 1) ? 9.81f : 0.f);  \
    if (lane < 32){                                                             \
      if (r16 < 3) accM += R_*R_;                                               \
      else if (r16 == 3){ float Rc_ = c00_ + c11_ + c22_; accC += Rc_*Rc_; }    \
    }                                                                           \
  } while (0)

  // ---------------- prologue: layer-1 of tile 0 ----------------
  L1_TILE(blk*TILES*TPB, jA);
  __syncthreads();

  // ---------------- main pipelined loop ----------------
  for (int i = 0; i < TILES; ++i){
    // int1: GEMM2(i) from jA  ||  layer-1(i+1) -> jB
    f32x4 acc[2][4];
    #pragma unroll
    for (int a = 0; a < 2; ++a)
      #pragma unroll
      for (int b = 0; b < 4; ++b)
        acc[a][b] = (f32x4){0.f, 0.f, 0.f, 0.f};
    GEMM2_TILE(jA, acc);
    if (i < TILES-1) L1_TILE((blk*TILES + i + 1)*TPB, jB);
    __syncthreads();

    // int2: recombine(i) -> jA  ||  GEMM3(i-1)+tail from jC (waves 4-7)
    RC_TILE(jA, acc);
    if (i > 0 && wid >= 4) GEMM3_TAIL(jC, (blk*TILES + i - 1)*TPB);
    __syncthreads();

    unsigned char* tmp = jA; jA = jB; jB = jC; jC = tmp;
  }
  // epilogue: GEMM3 of the last tile (its jet sits in jC after rotation)
  if (wid >= 4) GEMM3_TAIL(jC, (blk*TILES + TILES - 1)*TPB);

  // ---------------- block reduction (deterministic) ----------------
  #pragma unroll
  for (int off = 1; off < 64; off <<= 1){
    accM += __shfl_xor(accM, off, 64);
    accC += __shfl_xor(accC, off, 64);
  }
  __syncthreads();                 // done with the LDS ring
  float* red = (float*)sA;
  if (lane == 0){ red[wid*2] = accM; red[wid*2+1] = accC; }
  __syncthreads();
  if (t == 0){
    float m = 0.f, c = 0.f;
    #pragma unroll
    for (int w = 0; w < 8; ++w){ m += red[w*2]; c += red[w*2+1]; }
    float2 pr; pr.x = m; pr.y = c;
    *(float2*)(parts + blk*2) = pr;
  }
#undef L1_TILE
#undef GEMM2_TILE
#undef RC_TILE
#undef GEMM3_TAIL
}

__global__ void ns_reduce(const float* __restrict__ parts, float* __restrict__ out){
  int t = threadIdx.x;
  float a = 0.f, b = 0.f;
  if (t < NBLOCKS){ a = parts[2*t]; b = parts[2*t + 1]; }
  #pragma unroll
  for (int off = 32; off; off >>= 1){
    a += __shfl_down(a, off, 64);
    b += __shfl_down(b, off, 64);
  }
  __shared__ float sa[4], sb[4];
  int wid = t >> 6, lane = t & 63;
  if (lane == 0){ sa[wid] = a; sb[wid] = b; }
  __syncthreads();
  if (t == 0){
    float A = sa[0] + sa[1] + sa[2] + sa[3];
    float B = sb[0] + sb[1] + sb[2] + sb[3];
    float mom  = A / (float)NPTS;
    float cont = B / (float)NPTS;
    out[0] = mom + 10.f * cont;
    out[1] = mom;
    out[2] = cont;
  }
}

extern "C" void kernel_launch(void* const* d_in, const int* in_sizes, int n_in,
                              void* d_out, int out_size, void* d_ws, size_t ws_size,
                              hipStream_t stream) {
  const float* pts   = (const float*)d_in[0];
  const float* times = (const float*)d_in[1];
  const float* visc  = (const float*)d_in[2];
  const float* W1    = (const float*)d_in[3];
  const float* b1    = (const float*)d_in[4];
  const float* W2    = (const float*)d_in[5];
  const float* b2    = (const float*)d_in[6];
  const float* W3    = (const float*)d_in[7];
  const float* b3    = (const float*)d_in[8];
  float* out = (float*)d_out;

  unsigned short* w2t = (unsigned short*)d_ws;
  unsigned short* w3t = (unsigned short*)((char*)d_ws + W3T_OFF);
  float* parts        = (float*)((char*)d_ws + PART_OFF);

  prep_w2t<<<256, 256, 0, stream>>>(W2, w2t);
  prep_w3t<<<16, 256, 0, stream>>>(W3, w3t);
  ns_main<<<NBLOCKS, 512, 0, stream>>>(pts, times, visc, W1, b1, b2, b3, w2t, w3t, parts);
  ns_reduce<<<1, 256, 0, stream>>>(parts, out);
}